// Round 1
// 203.248 us; speedup vs baseline: 1.0181x; 1.0181x over previous
//
#include <hip/hip_runtime.h>

// CRF score reduction: B=512, S=2048, T=32.
// total = sum_b rowsum(trans[tags[b,0]])
//       + sum_b sum_T em[b,0,:]
//       + sum_{t>=1} em[b,t,:]*mask[b,t]
//       + 32 * sum_{t>=1} trans[tags[b,t-1],tags[b,t]]*mask[b,t]
//
// Branchless emissions stream (always *mask), t==0 correction folded into
// the sparse t0==0 branch of the tag loop. Grid geometry chosen so the
// emissions loop is EXACTLY 16 iterations/thread -> fully unrolled, all 16
// dwordx4 loads in flight before the adds (max MLP).
//
// Changes vs previous version (206.9 us measured, kernel itself <77 us per
// rocprof -- the window also contains ~156 us of harness 512-MiB poison
// fills):
//  1. Dropped __builtin_nontemporal_load -> plain dwordx4 (nt path is an
//     unverified-throughput suspect; regular path demonstrably hits 6.9 TB/s).
//  2. No hipMemsetAsync / no atomicAdd: per-block partials go to d_ws
//     (plain stores over poison, no init needed) and a 1-block finalize
//     kernel OVERWRITES out[0]. Removes the memset graph node.
//
// Mandatory HBM traffic: 128 MiB em + 4 MiB tags + 4 MiB mask = 137 MiB
// -> ~21 us at ~6.9 TB/s.

constexpr int BB = 512;
constexpr int SS = 2048;
constexpr int TT = 32;

constexpr int BLOCKS  = 2048;
constexpr int THREADS = 256;
constexpr int GSIZE   = BLOCKS * THREADS;           // 524,288
constexpr int N4      = BB * SS * TT / 4;           // 8,388,608
constexpr int EM_ITERS = N4 / GSIZE;                // exactly 16
static_assert(N4 % GSIZE == 0, "exact tiling");

typedef float f4v __attribute__((ext_vector_type(4)));

__global__ __launch_bounds__(THREADS) void crf_partial_kernel(
    const float* __restrict__ emissions,
    const int*   __restrict__ tags,
    const float* __restrict__ mask,
    const float* __restrict__ transitions,
    float*       __restrict__ partials)
{
    __shared__ float s_trans[TT * TT];
    __shared__ float s_rowsum[TT];
    __shared__ float s_red[4];

    const int tid  = threadIdx.x;
    const int gtid = blockIdx.x * THREADS + tid;

    // Stage 32x32 transitions in LDS (4 KiB), then per-tag rowsums.
    for (int i = tid; i < TT * TT; i += THREADS)
        s_trans[i] = transitions[i];
    __syncthreads();
    if (tid < TT) {
        float r = 0.f;
        #pragma unroll
        for (int k = 0; k < TT; ++k) r += s_trans[tid * TT + k];
        s_rowsum[tid] = r;
    }
    __syncthreads();

    // ---- emissions stream: 16 float4 loads, fully unrolled ----
    const f4v* em4 = (const f4v*)emissions;
    f4v   v[EM_ITERS];
    float w[EM_ITERS];
    #pragma unroll
    for (int k = 0; k < EM_ITERS; ++k) {
        int i = gtid + k * GSIZE;
        v[k] = em4[i];
        w[k] = mask[i >> 3];                  // (i*4)/32 -> (b*S + t)
    }
    float sum = 0.f;
    #pragma unroll
    for (int k = 0; k < EM_ITERS; ++k)
        sum += w[k] * ((v[k].x + v[k].y) + (v[k].z + v[k].w));

    // ---- tag-step stream: int4 tags + float4 mask, LDS gather ----
    // nu = 262,144 < GSIZE: each thread does 0 or 1 iterations.
    constexpr int NU = BB * SS / 4;
    if (gtid < NU) {
        const int u = gtid;
        int4   tg = ((const int4*)tags)[u];
        float4 mk = ((const float4*)mask)[u];
        int j0 = u * 4;
        int t0 = j0 & (SS - 1);
        if (t0 == 0) {
            // score0 transition rowsum + emissions t==0 mask correction
            sum += s_rowsum[tg.x];
            float r = 0.f;
            #pragma unroll
            for (int k = 0; k < TT / 4; ++k) {
                f4v e = ((const f4v*)(emissions + (size_t)j0 * TT))[k];
                r += (e.x + e.y) + (e.z + e.w);
            }
            sum += (1.0f - mk.x) * r;
        } else {
            int prev = tags[j0 - 1];
            sum += 32.0f * s_trans[prev * TT + tg.x] * mk.x;
        }
        sum += 32.0f * s_trans[tg.x * TT + tg.y] * mk.y;
        sum += 32.0f * s_trans[tg.y * TT + tg.z] * mk.z;
        sum += 32.0f * s_trans[tg.z * TT + tg.w] * mk.w;
    }

    // ---- wave (64) shuffle reduce, then cross-wave via LDS ----
    #pragma unroll
    for (int off = 32; off > 0; off >>= 1)
        sum += __shfl_down(sum, off, 64);
    const int lane = tid & 63;
    const int wave = tid >> 6;
    if (lane == 0) s_red[wave] = sum;
    __syncthreads();
    if (tid == 0) {
        // Plain store into workspace -- overwrites poison, no init needed.
        partials[blockIdx.x] = (s_red[0] + s_red[1]) + (s_red[2] + s_red[3]);
    }
}

__global__ __launch_bounds__(THREADS) void crf_finalize_kernel(
    const float* __restrict__ partials,
    float*       __restrict__ out)
{
    const int tid = threadIdx.x;
    float s = 0.f;
    #pragma unroll
    for (int k = 0; k < BLOCKS / THREADS; ++k)    // 8 iterations
        s += partials[tid + k * THREADS];
    #pragma unroll
    for (int off = 32; off > 0; off >>= 1)
        s += __shfl_down(s, off, 64);
    __shared__ float s_red[4];
    if ((tid & 63) == 0) s_red[tid >> 6] = s;
    __syncthreads();
    if (tid == 0)
        out[0] = (s_red[0] + s_red[1]) + (s_red[2] + s_red[3]);  // overwrite poison
}

extern "C" void kernel_launch(void* const* d_in, const int* in_sizes, int n_in,
                              void* d_out, int out_size, void* d_ws, size_t ws_size,
                              hipStream_t stream) {
    const float* emissions   = (const float*)d_in[0];
    const int*   tags        = (const int*)  d_in[1];
    const float* mask        = (const float*)d_in[2];
    const float* transitions = (const float*)d_in[3];
    float* partials = (float*)d_ws;           // 2048 floats = 8 KiB, plain-stored
    float* out      = (float*)d_out;

    crf_partial_kernel<<<BLOCKS, THREADS, 0, stream>>>(
        emissions, tags, mask, transitions, partials);
    crf_finalize_kernel<<<1, THREADS, 0, stream>>>(partials, out);
}